// Round 7
// baseline (291.764 us; speedup 1.0000x reference)
//
#include <hip/hip_runtime.h>
#include <math.h>

typedef __bf16 bf16;
typedef __bf16 bf16x4 __attribute__((ext_vector_type(4)));
typedef __bf16 bf16x8 __attribute__((ext_vector_type(8)));
typedef float floatx4 __attribute__((ext_vector_type(4)));

#define MFMA16(a, b, c) __builtin_amdgcn_mfma_f32_16x16x32_bf16(a, b, c, 0, 0, 0)

#if __has_builtin(__builtin_amdgcn_exp2f)
#define EXP2F(x) __builtin_amdgcn_exp2f(x)
#else
#define EXP2F(x) exp2f(x)
#endif

constexpr int Bc = 4, SQc = 2048, SKVc = 2048, Hc = 16, Dc = 64;
// fold 1/sqrt(D) * log2(e) into qh so softmax is exp2 with no extra mul
#define QSCALE 0.18033688011112042f

// Async global->LDS, 16B per lane. LDS dest is wave-uniform base + lane*16.
__device__ __forceinline__ void glds16(const bf16* g, bf16* lds_base, int lane) {
#if __has_builtin(__builtin_amdgcn_global_load_lds)
  __builtin_amdgcn_global_load_lds(
      (const __attribute__((address_space(1))) void*)g,
      (__attribute__((address_space(3))) void*)lds_base, 16, 0, 0);
#else
  *(bf16x8*)(lds_base + 8 * lane) = *(const bf16x8*)g;
#endif
}

// ---------------------------------------------------------------------------
// Prepass: fp32 -> bf16 convert (1024 elems per block)
// ---------------------------------------------------------------------------
__global__ void cvt_bf16(const float* __restrict__ in, bf16* __restrict__ out) {
  const size_t i = ((size_t)blockIdx.x * 256 + threadIdx.x) * 4;
  const float4 v = *(const float4*)&in[i];
  bf16x4 o = {(bf16)v.x, (bf16)v.y, (bf16)v.z, (bf16)v.w};
  *(bf16x4*)&out[i] = o;
}

// ---------------------------------------------------------------------------
// Prepass: RoPE cos/sin table. tab[pos*32 + f] = (cos, sin) of
// ang = pos * base^(-2f/64) = pos * 2^(-0.375 f).
// ---------------------------------------------------------------------------
__global__ void rope_tab_build(float2* __restrict__ tab) {
  const int i = blockIdx.x * 256 + threadIdx.x;  // 65536 = 2048 * 32
  const int pos = i >> 5, f = i & 31;
  const float ang = (float)pos * exp2f(-0.375f * (float)f);
  float sn, cs;
  sincosf(ang, &sn, &cs);
  tab[i] = make_float2(cs, sn);
}

// ---------------------------------------------------------------------------
// Prepass: W [K][N] fp32 -> WT [N][K] bf16. grid (N/64, K/64), 256 thr.
// ---------------------------------------------------------------------------
__global__ void transpose_cvt(const float* __restrict__ in, bf16* __restrict__ out,
                              int K, int N) {
  __shared__ bf16 T[64][72];
  const int tid = threadIdx.x;
  const int n0 = blockIdx.x * 64, k0 = blockIdx.y * 64;
  const int tr = tid >> 4, tc4 = (tid & 15) * 4;
#pragma unroll
  for (int i = 0; i < 4; i++) {
    const int k = tr + 16 * i;
    const float4 v = *(const float4*)&in[(size_t)(k0 + k) * N + n0 + tc4];
    T[tc4 + 0][k] = (bf16)v.x;
    T[tc4 + 1][k] = (bf16)v.y;
    T[tc4 + 2][k] = (bf16)v.z;
    T[tc4 + 3][k] = (bf16)v.w;
  }
  __syncthreads();
  const int nr = tid >> 2, kc = (tid & 3) * 8;
#pragma unroll
  for (int hf = 0; hf < 2; hf++)
    *(bf16x8*)&out[(size_t)(n0 + nr) * K + k0 + kc + 32 * hf] =
        *(const bf16x8*)&T[nr][kc + 32 * hf];
}

// ---------------------------------------------------------------------------
// Shared 128x128 / BK=64 K-loop, DOUBLE-BUFFERED global_load_lds staging.
// ---------------------------------------------------------------------------
__device__ __forceinline__ void gemm_kloop(const bf16* __restrict__ A,
                                           const bf16* __restrict__ BT, int m0,
                                           int n0, int tid, int wave, int lane,
                                           int m, int g, bf16 (*As)[128 * 64],
                                           bf16 (*Bs)[128 * 64],
                                           floatx4 (*acc)[4], int mq, int nq) {
  const int r_ = tid >> 3, p_ = tid & 7;
  const bf16* pA[4];
  const bf16* pB[4];
#pragma unroll
  for (int q = 0; q < 4; q++) {
    const int r = r_ + q * 32;
    const int s = p_ ^ (r & 7);
    pA[q] = &A[(size_t)(m0 + r) * 1024 + 8 * s];
    pB[q] = &BT[(size_t)(n0 + r) * 1024 + 8 * s];
  }

  // prologue: stage tile 0 into buf 0
#pragma unroll
  for (int q = 0; q < 4; q++) {
    glds16(pA[q], &As[0][(q * 4 + wave) * 512], lane);
    glds16(pB[q], &Bs[0][(q * 4 + wave) * 512], lane);
  }
  __syncthreads();  // drains vmcnt(0) -> buf0 visible

  for (int t = 0; t < 16; ++t) {
    const int cur = t & 1;
    // issue next-tile loads first (overlap with this tile's compute)
    if (t < 15) {
      const int k0 = 64 * (t + 1);
#pragma unroll
      for (int q = 0; q < 4; q++) {
        glds16(pA[q] + k0, &As[cur ^ 1][(q * 4 + wave) * 512], lane);
        glds16(pB[q] + k0, &Bs[cur ^ 1][(q * 4 + wave) * 512], lane);
      }
    }
    // compute on buf[cur]
    bf16x8 bb[4][2];
#pragma unroll
    for (int j = 0; j < 4; j++) {
      const int row = nq + 16 * j + m;
#pragma unroll
      for (int kh = 0; kh < 2; kh++)
        bb[j][kh] =
            *(const bf16x8*)&Bs[cur][row * 64 + 8 * ((g + 4 * kh) ^ (row & 7))];
    }
#pragma unroll
    for (int i = 0; i < 4; i++) {
      const int row = mq + 16 * i + m;
      const bf16x8 a0 = *(const bf16x8*)&As[cur][row * 64 + 8 * (g ^ (row & 7))];
      const bf16x8 a1 =
          *(const bf16x8*)&As[cur][row * 64 + 8 * ((g + 4) ^ (row & 7))];
#pragma unroll
      for (int j = 0; j < 4; j++) {
        acc[i][j] = MFMA16(a0, bb[j][0], acc[i][j]);
        acc[i][j] = MFMA16(a1, bb[j][1], acc[i][j]);
      }
    }
    __syncthreads();  // all waves done reading buf[cur]; next-tile loads drained
  }
}

// ---------------------------------------------------------------------------
// Fused Q-proj + KV-proj. grid (64, 9): y<8 -> Q tiles (RoPE+QSCALE -> qh),
// y==8 -> KV tile. K and V are written to global in MFMA *fragment order*:
//   K elem (pos,d) -> chunk=(pos>>4)*2+(d>>5), lane=((d>>3)&3)*16+(pos&15), e=d&7
//   V elem (pos,d) -> chunk=(pos>>6)*8+(d>>4)*2+((pos>>5)&1),
//                     lane=((pos>>3)&3)*16+(d&15), e=pos&7
// so attn's fragment loads are lane-linear (16B*lane) -> 1KB contiguous per
// instruction instead of 16 scattered cache lines (L1-request-bound fix).
// ---------------------------------------------------------------------------
__global__ __launch_bounds__(256, 2) void gemm_qkv(
    const bf16* __restrict__ qA, const bf16* __restrict__ qBT,
    const float* __restrict__ qb, const bf16* __restrict__ kvA,
    const bf16* __restrict__ kvBT, const float* __restrict__ kvb,
    const float2* __restrict__ tab, bf16* __restrict__ qh,
    bf16* __restrict__ kko, bf16* __restrict__ vto) {
  __shared__ bf16 As[2][128 * 64];
  __shared__ bf16 Bs[2][128 * 64];

  const int tid = threadIdx.x, lane = tid & 63, wave = tid >> 6;
  const int m = lane & 15, g = lane >> 4;
  const int m0 = blockIdx.x * 128;
  const bool isQ = (blockIdx.y < 8);
  const int n0 = isQ ? blockIdx.y * 128 : 0;
  const bf16* A = isQ ? qA : kvA;
  const bf16* BT = isQ ? qBT : kvBT;
  const float* bias = isQ ? qb : kvb;
  const int mq = (wave >> 1) * 64, nq = (wave & 1) * 64;

  floatx4 z = {0.f, 0.f, 0.f, 0.f};
  floatx4 acc[4][4];
#pragma unroll
  for (int i = 0; i < 4; i++)
#pragma unroll
    for (int j = 0; j < 4; j++) acc[i][j] = z;

  gemm_kloop(A, BT, m0, n0, tid, wave, lane, m, g, As, Bs, acc, mq, nq);

  const int rq = 4 * g;
#pragma unroll
  for (int j = 0; j < 4; j++) {
    const int col = n0 + nq + 16 * j + m;
    const float bv = bias[col];
#pragma unroll
    for (int i = 0; i < 4; i++) {
#pragma unroll
      for (int r = 0; r < 4; r++) {
        const int row = m0 + mq + 16 * i + rq + r;
        float v = acc[i][j][r] + bv;
        const float vp = __shfl_xor(v, 1);
        if (isQ) {
          const int d = col & 63, hh = col >> 6;
          const int pos = row & (SQc - 1), b = row >> 11;
          const float2 cssn = tab[pos * 32 + (d >> 1)];
          const float res = (d & 1) ? (v * cssn.x + vp * cssn.y)
                                    : (v * cssn.x - vp * cssn.y);
          qh[(((size_t)(b * Hc + hh) * SQc) + pos) * Dc + d] = (bf16)(res * QSCALE);
        } else {
          const int pos = row & (SKVc - 1), b = row >> 11;
          const size_t fb = (size_t)b * (SKVc * Dc);
          if (col < 64) {  // wave-uniform (nq is 0 or 64): K with RoPE
            const int d = col;
            const float2 cssn = tab[pos * 32 + (d >> 1)];
            const float res = (d & 1) ? (v * cssn.x + vp * cssn.y)
                                      : (v * cssn.x - vp * cssn.y);
            const int kc = (pos >> 4) * 2 + (d >> 5);
            const int kl = ((d >> 3) & 3) * 16 + (pos & 15);
            kko[fb + (size_t)kc * 512 + kl * 8 + (d & 7)] = (bf16)res;
          } else {
            const int d = col - 64;
            const int vc = (pos >> 6) * 8 + (d >> 4) * 2 + ((pos >> 5) & 1);
            const int vl = ((pos >> 3) & 3) * 16 + (d & 15);
            vto[fb + (size_t)vc * 512 + vl * 8 + (pos & 7)] = (bf16)v;
          }
        }
      }
    }
  }
}

// ---------------------------------------------------------------------------
// O-projection: fp32 out. grid (64, 8).
// ---------------------------------------------------------------------------
__global__ __launch_bounds__(256, 2) void gemm_out(
    const bf16* __restrict__ A, const bf16* __restrict__ BT,
    const float* __restrict__ bias, float* __restrict__ out) {
  __shared__ bf16 As[2][128 * 64];
  __shared__ bf16 Bs[2][128 * 64];

  const int tid = threadIdx.x, lane = tid & 63, wave = tid >> 6;
  const int m = lane & 15, g = lane >> 4;
  const int m0 = blockIdx.x * 128, n0 = blockIdx.y * 128;
  const int mq = (wave >> 1) * 64, nq = (wave & 1) * 64;

  floatx4 z = {0.f, 0.f, 0.f, 0.f};
  floatx4 acc[4][4];
#pragma unroll
  for (int i = 0; i < 4; i++)
#pragma unroll
    for (int j = 0; j < 4; j++) acc[i][j] = z;

  gemm_kloop(A, BT, m0, n0, tid, wave, lane, m, g, As, Bs, acc, mq, nq);

  const int rq = 4 * g;
#pragma unroll
  for (int j = 0; j < 4; j++) {
    const int col = n0 + nq + 16 * j + m;
    const float bv = bias[col];
#pragma unroll
    for (int i = 0; i < 4; i++)
#pragma unroll
      for (int r = 0; r < 4; r++) {
        const int row = m0 + mq + 16 * i + rq + r;
        out[(size_t)row * 1024 + col] = acc[i][j][r] + bv;
      }
  }
}

// ---------------------------------------------------------------------------
// Flash attention v9: identical per-wave program to v8 (64 q-rows/wave,
// 4 s-blocks, private P buffers, fragment-ordered K/V, K prefetch), but
// repackaged as 2-wave (128-thread) blocks, grid 1024. Total waves and
// per-wave load count UNCHANGED (what sank R4); VGPR not squeezed (what
// sank R2: forced (128,4) -> 64 regs -> 1.8GB spill). LDS 17.4 KB/block ->
// 8 blocks/CU; natural VGPR ~112 -> 4 waves/SIMD (was 2), letting the
// QK->exp2->ds->PV chains of different waves overlap MFMA and VALU pipes.
// ---------------------------------------------------------------------------
__global__ __launch_bounds__(128, 2) void attn_v5(
    const bf16* __restrict__ qh, const bf16* __restrict__ kk,
    const bf16* __restrict__ vt, bf16* __restrict__ hout) {
  const int bid = blockIdx.x;
  const int qt = bid & 15, h = (bid >> 4) & 15, b = bid >> 8;
  const int tid = threadIdx.x, lane = tid & 63, wave = tid >> 6;
  const int m = lane & 15, g = lane >> 4;

  __shared__ bf16 Pb[2][4][16][68];  // [wave][s-block][q][key] - private per s

  const int q0 = qt * 128 + wave * 64;
  // Q fragments (B-operand: n=q in lane&15, k=d)
  const bf16* qp = qh + (((size_t)(b * Hc + h) * SQc) + q0 + m) * Dc + 8 * g;
  bf16x8 bq[4][2];
#pragma unroll
  for (int s = 0; s < 4; s++) {
    bq[s][0] = *(const bf16x8*)(qp + (size_t)(16 * s) * Dc);
    bq[s][1] = *(const bf16x8*)(qp + (size_t)(16 * s) * Dc + 32);
  }

  const bf16 one = (bf16)1.0f;
  const bf16x8 ones = {one, one, one, one, one, one, one, one};

  floatx4 z = {0.f, 0.f, 0.f, 0.f};
  floatx4 accO[4][4];
  floatx4 lacc[4] = {z, z, z, z};
#pragma unroll
  for (int s = 0; s < 4; s++)
#pragma unroll
    for (int t = 0; t < 4; t++) accO[s][t] = z;

  // fragment-ordered K/V bases; per-lane offset is 16B*lane
  const bf16* kfb = kk + (size_t)b * (SKVc * Dc) + 8 * lane;
  const bf16* vfb = vt + (size_t)b * (SKVc * Dc) + 8 * lane;

  // preload K fragments for iteration 0 (chunks 0..7)
  bf16x8 kf[4][2];
#pragma unroll
  for (int c = 0; c < 4; c++) {
    kf[c][0] = *(const bf16x8*)(kfb + (size_t)(2 * c + 0) * 512);
    kf[c][1] = *(const bf16x8*)(kfb + (size_t)(2 * c + 1) * 512);
  }

  for (int it = 0; it < 32; ++it) {
    // ---- V loads for current iter (chunks it*8 .. it*8+7) ----
    bf16x8 vf[4][2];
#pragma unroll
    for (int t = 0; t < 4; t++) {
      vf[t][0] = *(const bf16x8*)(vfb + (size_t)(it * 8 + 2 * t + 0) * 512);
      vf[t][1] = *(const bf16x8*)(vfb + (size_t)(it * 8 + 2 * t + 1) * 512);
    }
    // ---- K prefetch for next iter ----
    bf16x8 kn[4][2];
    if (it + 1 < 32) {
#pragma unroll
      for (int c = 0; c < 4; c++) {
        kn[c][0] = *(const bf16x8*)(kfb + (size_t)((it + 1) * 8 + 2 * c + 0) * 512);
        kn[c][1] = *(const bf16x8*)(kfb + (size_t)((it + 1) * 8 + 2 * c + 1) * 512);
      }
    }
    // ---- phase 1: all s-blocks QK + exp2 + ds_write (independent buffers) --
#pragma unroll
    for (int s = 0; s < 4; s++) {
#pragma unroll
      for (int c = 0; c < 4; c++) {
        floatx4 sv = MFMA16(kf[c][0], bq[s][0], z);
        sv = MFMA16(kf[c][1], bq[s][1], sv);
        bf16x4 pk = {(bf16)EXP2F(sv[0]), (bf16)EXP2F(sv[1]), (bf16)EXP2F(sv[2]),
                     (bf16)EXP2F(sv[3])};
        *(bf16x4*)&Pb[wave][s][m][16 * c + 4 * g] = pk;
      }
    }
    // ---- phase 2: per s-block read P (A-layout) and accumulate PV ----
#pragma unroll
    for (int s = 0; s < 4; s++) {
      const bf16x8 pa0 = *(const bf16x8*)&Pb[wave][s][m][8 * g];
      const bf16x8 pa1 = *(const bf16x8*)&Pb[wave][s][m][32 + 8 * g];
      lacc[s] = MFMA16(pa0, ones, lacc[s]);
      lacc[s] = MFMA16(pa1, ones, lacc[s]);
#pragma unroll
      for (int t = 0; t < 4; t++) {
        accO[s][t] = MFMA16(pa0, vf[t][0], accO[s][t]);
        accO[s][t] = MFMA16(pa1, vf[t][1], accO[s][t]);
      }
    }
#pragma unroll
    for (int c = 0; c < 4; c++) {
      kf[c][0] = kn[c][0];
      kf[c][1] = kn[c][1];
    }
  }

  // ---- normalize and store h[b][s][h*64+d] ----
#pragma unroll
  for (int s = 0; s < 4; s++) {
    floatx4 inv;
#pragma unroll
    for (int r = 0; r < 4; r++) inv[r] = 1.0f / lacc[s][r];
#pragma unroll
    for (int t = 0; t < 4; t++)
#pragma unroll
      for (int r = 0; r < 4; r++) {
        const int qrow = q0 + 16 * s + 4 * g + r;
        hout[((size_t)(b * SQc + qrow)) * (Hc * Dc) + h * Dc + 16 * t + m] =
            (bf16)(accO[s][t][r] * inv[r]);
      }
  }
}

// ---------------------------------------------------------------------------
extern "C" void kernel_launch(void* const* d_in, const int* in_sizes, int n_in,
                              void* d_out, int out_size, void* d_ws, size_t ws_size,
                              hipStream_t stream) {
  const float* q = (const float*)d_in[0];
  const float* kv = (const float*)d_in[1];
  const float* Wq = (const float*)d_in[2];
  const float* bq = (const float*)d_in[3];
  const float* Wkv = (const float*)d_in[4];
  const float* bkv = (const float*)d_in[5];
  const float* Wo = (const float*)d_in[6];
  const float* bo = (const float*)d_in[7];

  char* ws = (char*)d_ws;
  bf16* qbf = (bf16*)ws;                            // 16 MiB (reused as hh later)
  bf16* kvbf = (bf16*)(ws + ((size_t)16 << 20));    // 16 MiB
  bf16* WqT = (bf16*)(ws + ((size_t)32 << 20));     // 2 MiB
  bf16* WkvT = (bf16*)(ws + ((size_t)34 << 20));    // 256 KiB
  float2* rtab = (float2*)(ws + ((size_t)34 << 20) + ((size_t)256 << 10));  // 512 KiB
  bf16* WoT = (bf16*)(ws + ((size_t)35 << 20));     // 2 MiB
  bf16* qh = (bf16*)(ws + ((size_t)37 << 20));      // 16 MiB
  bf16* kk = (bf16*)(ws + ((size_t)53 << 20));      // 1 MiB (fragment order)
  bf16* vt = (bf16*)(ws + ((size_t)54 << 20));      // 1 MiB (fragment order)
  bf16* hh = qbf;  // alias: qbf dead after gemm_qkv, hh written by attn

  const int M = Bc * SQc;  // 8192

  rope_tab_build<<<256, 256, 0, stream>>>(rtab);
  cvt_bf16<<<M, 256, 0, stream>>>(q, qbf);
  cvt_bf16<<<M, 256, 0, stream>>>(kv, kvbf);
  transpose_cvt<<<dim3(16, 16), 256, 0, stream>>>(Wq, WqT, 1024, 1024);
  transpose_cvt<<<dim3(2, 16), 256, 0, stream>>>(Wkv, WkvT, 1024, 128);
  transpose_cvt<<<dim3(16, 16), 256, 0, stream>>>(Wo, WoT, 1024, 1024);

  gemm_qkv<<<dim3(64, 9), 256, 0, stream>>>(qbf, WqT, bq, kvbf, WkvT, bkv, rtab,
                                            qh, kk, vt);
  attn_v5<<<Bc * Hc * (SQc / 128), 128, 0, stream>>>(qh, kk, vt, hh);
  gemm_out<<<dim3(64, 8), 256, 0, stream>>>(hh, WoT, bo, (float*)d_out);
}

// Round 8
// 284.934 us; speedup vs baseline: 1.0240x; 1.0240x over previous
//
#include <hip/hip_runtime.h>
#include <math.h>

typedef __bf16 bf16;
typedef __bf16 bf16x4 __attribute__((ext_vector_type(4)));
typedef __bf16 bf16x8 __attribute__((ext_vector_type(8)));
typedef float floatx4 __attribute__((ext_vector_type(4)));

#define MFMA16(a, b, c) __builtin_amdgcn_mfma_f32_16x16x32_bf16(a, b, c, 0, 0, 0)

#if __has_builtin(__builtin_amdgcn_exp2f)
#define EXP2F(x) __builtin_amdgcn_exp2f(x)
#else
#define EXP2F(x) exp2f(x)
#endif

constexpr int Bc = 4, SQc = 2048, SKVc = 2048, Hc = 16, Dc = 64;
// fold 1/sqrt(D) * log2(e) into qh so softmax is exp2 with no extra mul
#define QSCALE 0.18033688011112042f

// Async global->LDS, 16B per lane. LDS dest is wave-uniform base + lane*16;
// global source address is per-lane.
__device__ __forceinline__ void glds16(const bf16* g, bf16* lds_base, int lane) {
#if __has_builtin(__builtin_amdgcn_global_load_lds)
  __builtin_amdgcn_global_load_lds(
      (const __attribute__((address_space(1))) void*)g,
      (__attribute__((address_space(3))) void*)lds_base, 16, 0, 0);
#else
  *(bf16x8*)(lds_base + 8 * lane) = *(const bf16x8*)g;
#endif
}

// ---------------------------------------------------------------------------
// Prepass: fp32 -> bf16 convert (1024 elems per block)
// ---------------------------------------------------------------------------
__global__ void cvt_bf16(const float* __restrict__ in, bf16* __restrict__ out) {
  const size_t i = ((size_t)blockIdx.x * 256 + threadIdx.x) * 4;
  const float4 v = *(const float4*)&in[i];
  bf16x4 o = {(bf16)v.x, (bf16)v.y, (bf16)v.z, (bf16)v.w};
  *(bf16x4*)&out[i] = o;
}

// ---------------------------------------------------------------------------
// Prepass: RoPE cos/sin table. tab[pos*32 + f] = (cos, sin) of
// ang = pos * base^(-2f/64) = pos * 2^(-0.375 f).
// ---------------------------------------------------------------------------
__global__ void rope_tab_build(float2* __restrict__ tab) {
  const int i = blockIdx.x * 256 + threadIdx.x;  // 65536 = 2048 * 32
  const int pos = i >> 5, f = i & 31;
  const float ang = (float)pos * exp2f(-0.375f * (float)f);
  float sn, cs;
  sincosf(ang, &sn, &cs);
  tab[i] = make_float2(cs, sn);
}

// ---------------------------------------------------------------------------
// Prepass: W [K][N] fp32 -> WT [N][K] bf16. grid (N/64, K/64), 256 thr.
// ---------------------------------------------------------------------------
__global__ void transpose_cvt(const float* __restrict__ in, bf16* __restrict__ out,
                              int K, int N) {
  __shared__ bf16 T[64][72];
  const int tid = threadIdx.x;
  const int n0 = blockIdx.x * 64, k0 = blockIdx.y * 64;
  const int tr = tid >> 4, tc4 = (tid & 15) * 4;
#pragma unroll
  for (int i = 0; i < 4; i++) {
    const int k = tr + 16 * i;
    const float4 v = *(const float4*)&in[(size_t)(k0 + k) * N + n0 + tc4];
    T[tc4 + 0][k] = (bf16)v.x;
    T[tc4 + 1][k] = (bf16)v.y;
    T[tc4 + 2][k] = (bf16)v.z;
    T[tc4 + 3][k] = (bf16)v.w;
  }
  __syncthreads();
  const int nr = tid >> 2, kc = (tid & 3) * 8;
#pragma unroll
  for (int hf = 0; hf < 2; hf++)
    *(bf16x8*)&out[(size_t)(n0 + nr) * K + k0 + kc + 32 * hf] =
        *(const bf16x8*)&T[nr][kc + 32 * hf];
}

// ---------------------------------------------------------------------------
// Shared 128x128 / BK=64 K-loop, DOUBLE-BUFFERED global_load_lds staging.
// ---------------------------------------------------------------------------
__device__ __forceinline__ void gemm_kloop(const bf16* __restrict__ A,
                                           const bf16* __restrict__ BT, int m0,
                                           int n0, int tid, int wave, int lane,
                                           int m, int g, bf16 (*As)[128 * 64],
                                           bf16 (*Bs)[128 * 64],
                                           floatx4 (*acc)[4], int mq, int nq) {
  const int r_ = tid >> 3, p_ = tid & 7;
  const bf16* pA[4];
  const bf16* pB[4];
#pragma unroll
  for (int q = 0; q < 4; q++) {
    const int r = r_ + q * 32;
    const int s = p_ ^ (r & 7);
    pA[q] = &A[(size_t)(m0 + r) * 1024 + 8 * s];
    pB[q] = &BT[(size_t)(n0 + r) * 1024 + 8 * s];
  }

  // prologue: stage tile 0 into buf 0
#pragma unroll
  for (int q = 0; q < 4; q++) {
    glds16(pA[q], &As[0][(q * 4 + wave) * 512], lane);
    glds16(pB[q], &Bs[0][(q * 4 + wave) * 512], lane);
  }
  __syncthreads();  // drains vmcnt(0) -> buf0 visible

  for (int t = 0; t < 16; ++t) {
    const int cur = t & 1;
    // issue next-tile loads first (overlap with this tile's compute)
    if (t < 15) {
      const int k0 = 64 * (t + 1);
#pragma unroll
      for (int q = 0; q < 4; q++) {
        glds16(pA[q] + k0, &As[cur ^ 1][(q * 4 + wave) * 512], lane);
        glds16(pB[q] + k0, &Bs[cur ^ 1][(q * 4 + wave) * 512], lane);
      }
    }
    // compute on buf[cur]
    bf16x8 bb[4][2];
#pragma unroll
    for (int j = 0; j < 4; j++) {
      const int row = nq + 16 * j + m;
#pragma unroll
      for (int kh = 0; kh < 2; kh++)
        bb[j][kh] =
            *(const bf16x8*)&Bs[cur][row * 64 + 8 * ((g + 4 * kh) ^ (row & 7))];
    }
#pragma unroll
    for (int i = 0; i < 4; i++) {
      const int row = mq + 16 * i + m;
      const bf16x8 a0 = *(const bf16x8*)&As[cur][row * 64 + 8 * (g ^ (row & 7))];
      const bf16x8 a1 =
          *(const bf16x8*)&As[cur][row * 64 + 8 * ((g + 4) ^ (row & 7))];
#pragma unroll
      for (int j = 0; j < 4; j++) {
        acc[i][j] = MFMA16(a0, bb[j][0], acc[i][j]);
        acc[i][j] = MFMA16(a1, bb[j][1], acc[i][j]);
      }
    }
    __syncthreads();  // all waves done reading buf[cur]; next-tile loads drained
  }
}

// ---------------------------------------------------------------------------
// Fused Q-proj + KV-proj. grid (64, 9): y<8 -> Q tiles (RoPE+QSCALE -> qh),
// y==8 -> KV tile. K and V are written to global in MFMA *fragment order*:
//   K elem (pos,d) -> chunk=(pos>>4)*2+(d>>5), lane=((d>>3)&3)*16+(pos&15), e=d&7
//   V elem (pos,d) -> chunk=(pos>>6)*8+(d>>4)*2+((pos>>5)&1),
//                     lane=((pos>>3)&3)*16+(d&15), e=pos&7
// so attn's fragment accesses are lane-linear (16B*lane).
// ---------------------------------------------------------------------------
__global__ __launch_bounds__(256, 2) void gemm_qkv(
    const bf16* __restrict__ qA, const bf16* __restrict__ qBT,
    const float* __restrict__ qb, const bf16* __restrict__ kvA,
    const bf16* __restrict__ kvBT, const float* __restrict__ kvb,
    const float2* __restrict__ tab, bf16* __restrict__ qh,
    bf16* __restrict__ kko, bf16* __restrict__ vto) {
  __shared__ bf16 As[2][128 * 64];
  __shared__ bf16 Bs[2][128 * 64];

  const int tid = threadIdx.x, lane = tid & 63, wave = tid >> 6;
  const int m = lane & 15, g = lane >> 4;
  const int m0 = blockIdx.x * 128;
  const bool isQ = (blockIdx.y < 8);
  const int n0 = isQ ? blockIdx.y * 128 : 0;
  const bf16* A = isQ ? qA : kvA;
  const bf16* BT = isQ ? qBT : kvBT;
  const float* bias = isQ ? qb : kvb;
  const int mq = (wave >> 1) * 64, nq = (wave & 1) * 64;

  floatx4 z = {0.f, 0.f, 0.f, 0.f};
  floatx4 acc[4][4];
#pragma unroll
  for (int i = 0; i < 4; i++)
#pragma unroll
    for (int j = 0; j < 4; j++) acc[i][j] = z;

  gemm_kloop(A, BT, m0, n0, tid, wave, lane, m, g, As, Bs, acc, mq, nq);

  const int rq = 4 * g;
#pragma unroll
  for (int j = 0; j < 4; j++) {
    const int col = n0 + nq + 16 * j + m;
    const float bv = bias[col];
#pragma unroll
    for (int i = 0; i < 4; i++) {
#pragma unroll
      for (int r = 0; r < 4; r++) {
        const int row = m0 + mq + 16 * i + rq + r;
        float v = acc[i][j][r] + bv;
        const float vp = __shfl_xor(v, 1);
        if (isQ) {
          const int d = col & 63, hh = col >> 6;
          const int pos = row & (SQc - 1), b = row >> 11;
          const float2 cssn = tab[pos * 32 + (d >> 1)];
          const float res = (d & 1) ? (v * cssn.x + vp * cssn.y)
                                    : (v * cssn.x - vp * cssn.y);
          qh[(((size_t)(b * Hc + hh) * SQc) + pos) * Dc + d] = (bf16)(res * QSCALE);
        } else {
          const int pos = row & (SKVc - 1), b = row >> 11;
          const size_t fb = (size_t)b * (SKVc * Dc);
          if (col < 64) {  // wave-uniform (nq is 0 or 64): K with RoPE
            const int d = col;
            const float2 cssn = tab[pos * 32 + (d >> 1)];
            const float res = (d & 1) ? (v * cssn.x + vp * cssn.y)
                                      : (v * cssn.x - vp * cssn.y);
            const int kc = (pos >> 4) * 2 + (d >> 5);
            const int kl = ((d >> 3) & 3) * 16 + (pos & 15);
            kko[fb + (size_t)kc * 512 + kl * 8 + (d & 7)] = (bf16)res;
          } else {
            const int d = col - 64;
            const int vc = (pos >> 6) * 8 + (d >> 4) * 2 + ((pos >> 5) & 1);
            const int vl = ((pos >> 3) & 3) * 16 + (d & 15);
            vto[fb + (size_t)vc * 512 + vl * 8 + (pos & 7)] = (bf16)v;
          }
        }
      }
    }
  }
}

// ---------------------------------------------------------------------------
// O-projection: fp32 out. grid (64, 8).
// ---------------------------------------------------------------------------
__global__ __launch_bounds__(256, 2) void gemm_out(
    const bf16* __restrict__ A, const bf16* __restrict__ BT,
    const float* __restrict__ bias, float* __restrict__ out) {
  __shared__ bf16 As[2][128 * 64];
  __shared__ bf16 Bs[2][128 * 64];

  const int tid = threadIdx.x, lane = tid & 63, wave = tid >> 6;
  const int m = lane & 15, g = lane >> 4;
  const int m0 = blockIdx.x * 128, n0 = blockIdx.y * 128;
  const int mq = (wave >> 1) * 64, nq = (wave & 1) * 64;

  floatx4 z = {0.f, 0.f, 0.f, 0.f};
  floatx4 acc[4][4];
#pragma unroll
  for (int i = 0; i < 4; i++)
#pragma unroll
    for (int j = 0; j < 4; j++) acc[i][j] = z;

  gemm_kloop(A, BT, m0, n0, tid, wave, lane, m, g, As, Bs, acc, mq, nq);

  const int rq = 4 * g;
#pragma unroll
  for (int j = 0; j < 4; j++) {
    const int col = n0 + nq + 16 * j + m;
    const float bv = bias[col];
#pragma unroll
    for (int i = 0; i < 4; i++)
#pragma unroll
      for (int r = 0; r < 4; r++) {
        const int row = m0 + mq + 16 * i + rq + r;
        out[(size_t)row * 1024 + col] = acc[i][j][r] + bv;
      }
  }
}

// ---------------------------------------------------------------------------
// Flash attention v10: LDS-shared K/V. 8-wave (512-thr) blocks, 32 q-rows
// per wave, grid 512 -> 2 blocks/CU = 16 waves/CU = 4 waves/SIMD (was 2).
// Each block stages the 8KB K-tile (prefetch, double-buffered) and 8KB
// V-tile (single buffer) ONCE per iter via global_load_lds (fragment order
// = lane-linear glds), so per-CU global traffic drops 4x while wave count
// doubles -> MFMA/VALU pipes of phase-shifted waves can finally overlap.
// 2 barriers/iter: top (Vb reads of it-1 done before V(it) staging) and
// mid (staged data visible before phase 2). Total MFMA work conserved.
// ---------------------------------------------------------------------------
__global__ __launch_bounds__(512, 4) void attn_v5(
    const bf16* __restrict__ qh, const bf16* __restrict__ kk,
    const bf16* __restrict__ vt, bf16* __restrict__ hout) {
  const int bid = blockIdx.x;
  const int qt = bid & 7, h = (bid >> 3) & 15, b = bid >> 7;
  const int tid = threadIdx.x, lane = tid & 63, wave = tid >> 6;  // 8 waves
  const int m = lane & 15, g = lane >> 4;

  __shared__ bf16 Kb[2][4096];       // 16 KiB: K tile double buffer
  __shared__ bf16 Vb[4096];          // 8 KiB: V tile
  __shared__ bf16 Pb[8][2][16][68];  // 34 KiB: per-wave private P relayout

  const int q0 = qt * 256 + wave * 32;
  // Q fragments (B-operand: n=q in lane&15, k=d)
  const bf16* qp = qh + (((size_t)(b * Hc + h) * SQc) + q0 + m) * Dc + 8 * g;
  bf16x8 bq[2][2];
#pragma unroll
  for (int s = 0; s < 2; s++) {
    bq[s][0] = *(const bf16x8*)(qp + (size_t)(16 * s) * Dc);
    bq[s][1] = *(const bf16x8*)(qp + (size_t)(16 * s) * Dc + 32);
  }

  const bf16 one = (bf16)1.0f;
  const bf16x8 ones = {one, one, one, one, one, one, one, one};

  floatx4 z = {0.f, 0.f, 0.f, 0.f};
  floatx4 accO[2][4];
  floatx4 lacc[2] = {z, z};
#pragma unroll
  for (int s = 0; s < 2; s++)
#pragma unroll
    for (int t = 0; t < 4; t++) accO[s][t] = z;

  // fragment-ordered global bases (per-lane: +16B*lane)
  const size_t fb = (size_t)b * (SKVc * Dc);
  const bf16* kg = kk + fb + 8 * lane;
  const bf16* vg = vt + fb + 8 * lane;

  // prologue: stage K(0); wave w stages chunk w (1 KiB each)
  glds16(kg + (size_t)wave * 512, &Kb[0][wave * 512], lane);
  __syncthreads();

  for (int it = 0; it < 32; ++it) {
    const int cur = it & 1;
    // top barrier: previous iter's Vb reads complete before restaging
    if (it) __syncthreads();
    // stage V(it) and K(it+1): wave w handles chunk w of each
    glds16(vg + (size_t)(it * 8 + wave) * 512, &Vb[wave * 512], lane);
    if (it + 1 < 32)
      glds16(kg + (size_t)((it + 1) * 8 + wave) * 512, &Kb[cur ^ 1][wave * 512],
             lane);

    // ---- phase 1: QK + exp2 + Pb write (K tile shared from LDS) ----
    bf16x8 kfr[4][2];
#pragma unroll
    for (int c = 0; c < 4; c++) {
      kfr[c][0] = *(const bf16x8*)&Kb[cur][(2 * c + 0) * 512 + 8 * lane];
      kfr[c][1] = *(const bf16x8*)&Kb[cur][(2 * c + 1) * 512 + 8 * lane];
    }
#pragma unroll
    for (int s = 0; s < 2; s++) {
#pragma unroll
      for (int c = 0; c < 4; c++) {
        floatx4 sv = MFMA16(kfr[c][0], bq[s][0], z);
        sv = MFMA16(kfr[c][1], bq[s][1], sv);
        bf16x4 pk = {(bf16)EXP2F(sv[0]), (bf16)EXP2F(sv[1]), (bf16)EXP2F(sv[2]),
                     (bf16)EXP2F(sv[3])};
        *(bf16x4*)&Pb[wave][s][m][16 * c + 4 * g] = pk;
      }
    }
    __syncthreads();  // drains vmcnt: V(it)/K(it+1) landed; Kb[cur] reads done

    // ---- phase 2: read V fragments from LDS, P from Pb, accumulate ----
    bf16x8 vf[4][2];
#pragma unroll
    for (int t = 0; t < 4; t++) {
      vf[t][0] = *(const bf16x8*)&Vb[(2 * t + 0) * 512 + 8 * lane];
      vf[t][1] = *(const bf16x8*)&Vb[(2 * t + 1) * 512 + 8 * lane];
    }
#pragma unroll
    for (int s = 0; s < 2; s++) {
      const bf16x8 pa0 = *(const bf16x8*)&Pb[wave][s][m][8 * g];
      const bf16x8 pa1 = *(const bf16x8*)&Pb[wave][s][m][32 + 8 * g];
      lacc[s] = MFMA16(pa0, ones, lacc[s]);
      lacc[s] = MFMA16(pa1, ones, lacc[s]);
#pragma unroll
      for (int t = 0; t < 4; t++) {
        accO[s][t] = MFMA16(pa0, vf[t][0], accO[s][t]);
        accO[s][t] = MFMA16(pa1, vf[t][1], accO[s][t]);
      }
    }
  }

  // ---- normalize and store h[b][s][h*64+d] ----
#pragma unroll
  for (int s = 0; s < 2; s++) {
    floatx4 inv;
#pragma unroll
    for (int r = 0; r < 4; r++) inv[r] = 1.0f / lacc[s][r];
#pragma unroll
    for (int t = 0; t < 4; t++)
#pragma unroll
      for (int r = 0; r < 4; r++) {
        const int qrow = q0 + 16 * s + 4 * g + r;
        hout[((size_t)(b * SQc + qrow)) * (Hc * Dc) + h * Dc + 16 * t + m] =
            (bf16)(accO[s][t][r] * inv[r]);
      }
  }
}

// ---------------------------------------------------------------------------
extern "C" void kernel_launch(void* const* d_in, const int* in_sizes, int n_in,
                              void* d_out, int out_size, void* d_ws, size_t ws_size,
                              hipStream_t stream) {
  const float* q = (const float*)d_in[0];
  const float* kv = (const float*)d_in[1];
  const float* Wq = (const float*)d_in[2];
  const float* bq = (const float*)d_in[3];
  const float* Wkv = (const float*)d_in[4];
  const float* bkv = (const float*)d_in[5];
  const float* Wo = (const float*)d_in[6];
  const float* bo = (const float*)d_in[7];

  char* ws = (char*)d_ws;
  bf16* qbf = (bf16*)ws;                            // 16 MiB (reused as hh later)
  bf16* kvbf = (bf16*)(ws + ((size_t)16 << 20));    // 16 MiB
  bf16* WqT = (bf16*)(ws + ((size_t)32 << 20));     // 2 MiB
  bf16* WkvT = (bf16*)(ws + ((size_t)34 << 20));    // 256 KiB
  float2* rtab = (float2*)(ws + ((size_t)34 << 20) + ((size_t)256 << 10));  // 512 KiB
  bf16* WoT = (bf16*)(ws + ((size_t)35 << 20));     // 2 MiB
  bf16* qh = (bf16*)(ws + ((size_t)37 << 20));      // 16 MiB
  bf16* kk = (bf16*)(ws + ((size_t)53 << 20));      // 1 MiB (fragment order)
  bf16* vt = (bf16*)(ws + ((size_t)54 << 20));      // 1 MiB (fragment order)
  bf16* hh = qbf;  // alias: qbf dead after gemm_qkv, hh written by attn

  const int M = Bc * SQc;  // 8192

  rope_tab_build<<<256, 256, 0, stream>>>(rtab);
  cvt_bf16<<<M, 256, 0, stream>>>(q, qbf);
  cvt_bf16<<<M, 256, 0, stream>>>(kv, kvbf);
  transpose_cvt<<<dim3(16, 16), 256, 0, stream>>>(Wq, WqT, 1024, 1024);
  transpose_cvt<<<dim3(2, 16), 256, 0, stream>>>(Wkv, WkvT, 1024, 128);
  transpose_cvt<<<dim3(16, 16), 256, 0, stream>>>(Wo, WoT, 1024, 1024);

  gemm_qkv<<<dim3(64, 9), 256, 0, stream>>>(qbf, WqT, bq, kvbf, WkvT, bkv, rtab,
                                            qh, kk, vt);
  attn_v5<<<Bc * Hc * (SQc / 256), 512, 0, stream>>>(qh, kk, vt, hh);
  gemm_out<<<dim3(64, 8), 256, 0, stream>>>(hh, WoT, bo, (float*)d_out);
}

// Round 9
// 261.431 us; speedup vs baseline: 1.1160x; 1.0899x over previous
//
#include <hip/hip_runtime.h>
#include <math.h>

typedef __bf16 bf16;
typedef __bf16 bf16x4 __attribute__((ext_vector_type(4)));
typedef __bf16 bf16x8 __attribute__((ext_vector_type(8)));
typedef float floatx4 __attribute__((ext_vector_type(4)));

#define MFMA16(a, b, c) __builtin_amdgcn_mfma_f32_16x16x32_bf16(a, b, c, 0, 0, 0)

#if __has_builtin(__builtin_amdgcn_exp2f)
#define EXP2F(x) __builtin_amdgcn_exp2f(x)
#else
#define EXP2F(x) exp2f(x)
#endif

constexpr int Bc = 4, SQc = 2048, SKVc = 2048, Hc = 16, Dc = 64;
// fold 1/sqrt(D) * log2(e) into qh so softmax is exp2 with no extra mul
#define QSCALE 0.18033688011112042f

// Async global->LDS, 16B per lane. LDS dest is wave-uniform base + lane*16;
// global source address is per-lane.
__device__ __forceinline__ void glds16(const bf16* g, bf16* lds_base, int lane) {
#if __has_builtin(__builtin_amdgcn_global_load_lds)
  __builtin_amdgcn_global_load_lds(
      (const __attribute__((address_space(1))) void*)g,
      (__attribute__((address_space(3))) void*)lds_base, 16, 0, 0);
#else
  *(bf16x8*)(lds_base + 8 * lane) = *(const bf16x8*)g;
#endif
}

// ---------------------------------------------------------------------------
// Prepass: fp32 -> bf16 convert (1024 elems per block)
// ---------------------------------------------------------------------------
__global__ void cvt_bf16(const float* __restrict__ in, bf16* __restrict__ out) {
  const size_t i = ((size_t)blockIdx.x * 256 + threadIdx.x) * 4;
  const float4 v = *(const float4*)&in[i];
  bf16x4 o = {(bf16)v.x, (bf16)v.y, (bf16)v.z, (bf16)v.w};
  *(bf16x4*)&out[i] = o;
}

// ---------------------------------------------------------------------------
// Prepass: RoPE cos/sin table. tab[pos*32 + f] = (cos, sin) of
// ang = pos * base^(-2f/64) = pos * 2^(-0.375 f).
// ---------------------------------------------------------------------------
__global__ void rope_tab_build(float2* __restrict__ tab) {
  const int i = blockIdx.x * 256 + threadIdx.x;  // 65536 = 2048 * 32
  const int pos = i >> 5, f = i & 31;
  const float ang = (float)pos * exp2f(-0.375f * (float)f);
  float sn, cs;
  sincosf(ang, &sn, &cs);
  tab[i] = make_float2(cs, sn);
}

// ---------------------------------------------------------------------------
// Prepass: W [K][N] fp32 -> WT [N][K] bf16. grid (N/64, K/64), 256 thr.
// ---------------------------------------------------------------------------
__global__ void transpose_cvt(const float* __restrict__ in, bf16* __restrict__ out,
                              int K, int N) {
  __shared__ bf16 T[64][72];
  const int tid = threadIdx.x;
  const int n0 = blockIdx.x * 64, k0 = blockIdx.y * 64;
  const int tr = tid >> 4, tc4 = (tid & 15) * 4;
#pragma unroll
  for (int i = 0; i < 4; i++) {
    const int k = tr + 16 * i;
    const float4 v = *(const float4*)&in[(size_t)(k0 + k) * N + n0 + tc4];
    T[tc4 + 0][k] = (bf16)v.x;
    T[tc4 + 1][k] = (bf16)v.y;
    T[tc4 + 2][k] = (bf16)v.z;
    T[tc4 + 3][k] = (bf16)v.w;
  }
  __syncthreads();
  const int nr = tid >> 2, kc = (tid & 3) * 8;
#pragma unroll
  for (int hf = 0; hf < 2; hf++)
    *(bf16x8*)&out[(size_t)(n0 + nr) * K + k0 + kc + 32 * hf] =
        *(const bf16x8*)&T[nr][kc + 32 * hf];
}

// ---------------------------------------------------------------------------
// Shared 128x128 / BK=64 K-loop — m97-exact single-buffered 2-barrier loop.
// R1's explicit double-buffer doubled LDS to 64KB and cut occupancy 3->2
// blocks/CU (the m132 regression); single-buffer at 32KB restores 3/CU, and
// implicit wave-level overlap captures the prefetch benefit (m131-m140).
// ---------------------------------------------------------------------------
__device__ __forceinline__ void gemm_kloop(const bf16* __restrict__ A,
                                           const bf16* __restrict__ BT, int m0,
                                           int n0, int tid, int wave, int lane,
                                           int m, int g, bf16* As, bf16* Bs,
                                           floatx4 (*acc)[4], int mq, int nq) {
  const int r_ = tid >> 3, p_ = tid & 7;
  const bf16* pA[4];
  const bf16* pB[4];
#pragma unroll
  for (int q = 0; q < 4; q++) {
    const int r = r_ + q * 32;
    const int s = p_ ^ (r & 7);
    pA[q] = &A[(size_t)(m0 + r) * 1024 + 8 * s];
    pB[q] = &BT[(size_t)(n0 + r) * 1024 + 8 * s];
  }

  for (int k0 = 0; k0 < 1024; k0 += 64) {
    __syncthreads();
#pragma unroll
    for (int q = 0; q < 4; q++) {
      glds16(pA[q] + k0, &As[(q * 4 + wave) * 512], lane);
      glds16(pB[q] + k0, &Bs[(q * 4 + wave) * 512], lane);
    }
    __syncthreads();  // drains vmcnt -> LDS tiles visible

    bf16x8 bb[4][2];
#pragma unroll
    for (int j = 0; j < 4; j++) {
      const int row = nq + 16 * j + m;
#pragma unroll
      for (int kh = 0; kh < 2; kh++)
        bb[j][kh] = *(const bf16x8*)&Bs[row * 64 + 8 * ((g + 4 * kh) ^ (row & 7))];
    }
#pragma unroll
    for (int i = 0; i < 4; i++) {
      const int row = mq + 16 * i + m;
      const bf16x8 a0 = *(const bf16x8*)&As[row * 64 + 8 * (g ^ (row & 7))];
      const bf16x8 a1 = *(const bf16x8*)&As[row * 64 + 8 * ((g + 4) ^ (row & 7))];
#pragma unroll
      for (int j = 0; j < 4; j++) {
        acc[i][j] = MFMA16(a0, bb[j][0], acc[i][j]);
        acc[i][j] = MFMA16(a1, bb[j][1], acc[i][j]);
      }
    }
  }
}

// ---------------------------------------------------------------------------
// Fused Q-proj + KV-proj. grid (64, 9): y<8 -> Q tiles (RoPE+QSCALE -> qh),
// y==8 -> KV tile. K and V are written to global in MFMA *fragment order*:
//   K elem (pos,d) -> chunk=(pos>>4)*2+(d>>5), lane=((d>>3)&3)*16+(pos&15), e=d&7
//   V elem (pos,d) -> chunk=(pos>>6)*8+(d>>4)*2+((pos>>5)&1),
//                     lane=((pos>>3)&3)*16+(d&15), e=pos&7
// so attn's fragment accesses are lane-linear (16B*lane).
// ---------------------------------------------------------------------------
__global__ __launch_bounds__(256, 3) void gemm_qkv(
    const bf16* __restrict__ qA, const bf16* __restrict__ qBT,
    const float* __restrict__ qb, const bf16* __restrict__ kvA,
    const bf16* __restrict__ kvBT, const float* __restrict__ kvb,
    const float2* __restrict__ tab, bf16* __restrict__ qh,
    bf16* __restrict__ kko, bf16* __restrict__ vto) {
  __shared__ bf16 As[128 * 64];
  __shared__ bf16 Bs[128 * 64];

  const int tid = threadIdx.x, lane = tid & 63, wave = tid >> 6;
  const int m = lane & 15, g = lane >> 4;
  const int m0 = blockIdx.x * 128;
  const bool isQ = (blockIdx.y < 8);
  const int n0 = isQ ? blockIdx.y * 128 : 0;
  const bf16* A = isQ ? qA : kvA;
  const bf16* BT = isQ ? qBT : kvBT;
  const float* bias = isQ ? qb : kvb;
  const int mq = (wave >> 1) * 64, nq = (wave & 1) * 64;

  floatx4 z = {0.f, 0.f, 0.f, 0.f};
  floatx4 acc[4][4];
#pragma unroll
  for (int i = 0; i < 4; i++)
#pragma unroll
    for (int j = 0; j < 4; j++) acc[i][j] = z;

  gemm_kloop(A, BT, m0, n0, tid, wave, lane, m, g, As, Bs, acc, mq, nq);

  const int rq = 4 * g;
#pragma unroll
  for (int j = 0; j < 4; j++) {
    const int col = n0 + nq + 16 * j + m;
    const float bv = bias[col];
#pragma unroll
    for (int i = 0; i < 4; i++) {
#pragma unroll
      for (int r = 0; r < 4; r++) {
        const int row = m0 + mq + 16 * i + rq + r;
        float v = acc[i][j][r] + bv;
        const float vp = __shfl_xor(v, 1);
        if (isQ) {
          const int d = col & 63, hh = col >> 6;
          const int pos = row & (SQc - 1), b = row >> 11;
          const float2 cssn = tab[pos * 32 + (d >> 1)];
          const float res = (d & 1) ? (v * cssn.x + vp * cssn.y)
                                    : (v * cssn.x - vp * cssn.y);
          qh[(((size_t)(b * Hc + hh) * SQc) + pos) * Dc + d] = (bf16)(res * QSCALE);
        } else {
          const int pos = row & (SKVc - 1), b = row >> 11;
          const size_t fb = (size_t)b * (SKVc * Dc);
          if (col < 64) {  // wave-uniform (nq is 0 or 64): K with RoPE
            const int d = col;
            const float2 cssn = tab[pos * 32 + (d >> 1)];
            const float res = (d & 1) ? (v * cssn.x + vp * cssn.y)
                                      : (v * cssn.x - vp * cssn.y);
            const int kc = (pos >> 4) * 2 + (d >> 5);
            const int kl = ((d >> 3) & 3) * 16 + (pos & 15);
            kko[fb + (size_t)kc * 512 + kl * 8 + (d & 7)] = (bf16)res;
          } else {
            const int d = col - 64;
            const int vc = (pos >> 6) * 8 + (d >> 4) * 2 + ((pos >> 5) & 1);
            const int vl = ((pos >> 3) & 3) * 16 + (d & 15);
            vto[fb + (size_t)vc * 512 + vl * 8 + (pos & 7)] = (bf16)v;
          }
        }
      }
    }
  }
}

// ---------------------------------------------------------------------------
// O-projection: fp32 out. grid (64, 8).
// ---------------------------------------------------------------------------
__global__ __launch_bounds__(256, 3) void gemm_out(
    const bf16* __restrict__ A, const bf16* __restrict__ BT,
    const float* __restrict__ bias, float* __restrict__ out) {
  __shared__ bf16 As[128 * 64];
  __shared__ bf16 Bs[128 * 64];

  const int tid = threadIdx.x, lane = tid & 63, wave = tid >> 6;
  const int m = lane & 15, g = lane >> 4;
  const int m0 = blockIdx.x * 128, n0 = blockIdx.y * 128;
  const int mq = (wave >> 1) * 64, nq = (wave & 1) * 64;

  floatx4 z = {0.f, 0.f, 0.f, 0.f};
  floatx4 acc[4][4];
#pragma unroll
  for (int i = 0; i < 4; i++)
#pragma unroll
    for (int j = 0; j < 4; j++) acc[i][j] = z;

  gemm_kloop(A, BT, m0, n0, tid, wave, lane, m, g, As, Bs, acc, mq, nq);

  const int rq = 4 * g;
#pragma unroll
  for (int j = 0; j < 4; j++) {
    const int col = n0 + nq + 16 * j + m;
    const float bv = bias[col];
#pragma unroll
    for (int i = 0; i < 4; i++)
#pragma unroll
      for (int r = 0; r < 4; r++) {
        const int row = m0 + mq + 16 * i + rq + r;
        out[(size_t)row * 1024 + col] = acc[i][j][r] + bv;
      }
  }
}

// ---------------------------------------------------------------------------
// Flash attention v10 (unchanged from R8): LDS-shared K/V. 8-wave (512-thr)
// blocks, 32 q-rows per wave, grid 512 -> 16 waves/CU. Fragment-ordered K/V
// staged once per block per iter via global_load_lds; K double-buffered,
// V single-buffered; 2 barriers/iter.
// ---------------------------------------------------------------------------
__global__ __launch_bounds__(512, 4) void attn_v5(
    const bf16* __restrict__ qh, const bf16* __restrict__ kk,
    const bf16* __restrict__ vt, bf16* __restrict__ hout) {
  const int bid = blockIdx.x;
  const int qt = bid & 7, h = (bid >> 3) & 15, b = bid >> 7;
  const int tid = threadIdx.x, lane = tid & 63, wave = tid >> 6;  // 8 waves
  const int m = lane & 15, g = lane >> 4;

  __shared__ bf16 Kb[2][4096];       // 16 KiB: K tile double buffer
  __shared__ bf16 Vb[4096];          // 8 KiB: V tile
  __shared__ bf16 Pb[8][2][16][68];  // 34 KiB: per-wave private P relayout

  const int q0 = qt * 256 + wave * 32;
  // Q fragments (B-operand: n=q in lane&15, k=d)
  const bf16* qp = qh + (((size_t)(b * Hc + h) * SQc) + q0 + m) * Dc + 8 * g;
  bf16x8 bq[2][2];
#pragma unroll
  for (int s = 0; s < 2; s++) {
    bq[s][0] = *(const bf16x8*)(qp + (size_t)(16 * s) * Dc);
    bq[s][1] = *(const bf16x8*)(qp + (size_t)(16 * s) * Dc + 32);
  }

  const bf16 one = (bf16)1.0f;
  const bf16x8 ones = {one, one, one, one, one, one, one, one};

  floatx4 z = {0.f, 0.f, 0.f, 0.f};
  floatx4 accO[2][4];
  floatx4 lacc[2] = {z, z};
#pragma unroll
  for (int s = 0; s < 2; s++)
#pragma unroll
    for (int t = 0; t < 4; t++) accO[s][t] = z;

  // fragment-ordered global bases (per-lane: +16B*lane)
  const size_t fb = (size_t)b * (SKVc * Dc);
  const bf16* kg = kk + fb + 8 * lane;
  const bf16* vg = vt + fb + 8 * lane;

  // prologue: stage K(0); wave w stages chunk w (1 KiB each)
  glds16(kg + (size_t)wave * 512, &Kb[0][wave * 512], lane);
  __syncthreads();

  for (int it = 0; it < 32; ++it) {
    const int cur = it & 1;
    // top barrier: previous iter's Vb reads complete before restaging
    if (it) __syncthreads();
    // stage V(it) and K(it+1): wave w handles chunk w of each
    glds16(vg + (size_t)(it * 8 + wave) * 512, &Vb[wave * 512], lane);
    if (it + 1 < 32)
      glds16(kg + (size_t)((it + 1) * 8 + wave) * 512, &Kb[cur ^ 1][wave * 512],
             lane);

    // ---- phase 1: QK + exp2 + Pb write (K tile shared from LDS) ----
    bf16x8 kfr[4][2];
#pragma unroll
    for (int c = 0; c < 4; c++) {
      kfr[c][0] = *(const bf16x8*)&Kb[cur][(2 * c + 0) * 512 + 8 * lane];
      kfr[c][1] = *(const bf16x8*)&Kb[cur][(2 * c + 1) * 512 + 8 * lane];
    }
#pragma unroll
    for (int s = 0; s < 2; s++) {
#pragma unroll
      for (int c = 0; c < 4; c++) {
        floatx4 sv = MFMA16(kfr[c][0], bq[s][0], z);
        sv = MFMA16(kfr[c][1], bq[s][1], sv);
        bf16x4 pk = {(bf16)EXP2F(sv[0]), (bf16)EXP2F(sv[1]), (bf16)EXP2F(sv[2]),
                     (bf16)EXP2F(sv[3])};
        *(bf16x4*)&Pb[wave][s][m][16 * c + 4 * g] = pk;
      }
    }
    __syncthreads();  // drains vmcnt: V(it)/K(it+1) landed; Kb[cur] reads done

    // ---- phase 2: read V fragments from LDS, P from Pb, accumulate ----
    bf16x8 vf[4][2];
#pragma unroll
    for (int t = 0; t < 4; t++) {
      vf[t][0] = *(const bf16x8*)&Vb[(2 * t + 0) * 512 + 8 * lane];
      vf[t][1] = *(const bf16x8*)&Vb[(2 * t + 1) * 512 + 8 * lane];
    }
#pragma unroll
    for (int s = 0; s < 2; s++) {
      const bf16x8 pa0 = *(const bf16x8*)&Pb[wave][s][m][8 * g];
      const bf16x8 pa1 = *(const bf16x8*)&Pb[wave][s][m][32 + 8 * g];
      lacc[s] = MFMA16(pa0, ones, lacc[s]);
      lacc[s] = MFMA16(pa1, ones, lacc[s]);
#pragma unroll
      for (int t = 0; t < 4; t++) {
        accO[s][t] = MFMA16(pa0, vf[t][0], accO[s][t]);
        accO[s][t] = MFMA16(pa1, vf[t][1], accO[s][t]);
      }
    }
  }

  // ---- normalize and store h[b][s][h*64+d] ----
#pragma unroll
  for (int s = 0; s < 2; s++) {
    floatx4 inv;
#pragma unroll
    for (int r = 0; r < 4; r++) inv[r] = 1.0f / lacc[s][r];
#pragma unroll
    for (int t = 0; t < 4; t++)
#pragma unroll
      for (int r = 0; r < 4; r++) {
        const int qrow = q0 + 16 * s + 4 * g + r;
        hout[((size_t)(b * SQc + qrow)) * (Hc * Dc) + h * Dc + 16 * t + m] =
            (bf16)(accO[s][t][r] * inv[r]);
      }
  }
}

// ---------------------------------------------------------------------------
extern "C" void kernel_launch(void* const* d_in, const int* in_sizes, int n_in,
                              void* d_out, int out_size, void* d_ws, size_t ws_size,
                              hipStream_t stream) {
  const float* q = (const float*)d_in[0];
  const float* kv = (const float*)d_in[1];
  const float* Wq = (const float*)d_in[2];
  const float* bq = (const float*)d_in[3];
  const float* Wkv = (const float*)d_in[4];
  const float* bkv = (const float*)d_in[5];
  const float* Wo = (const float*)d_in[6];
  const float* bo = (const float*)d_in[7];

  char* ws = (char*)d_ws;
  bf16* qbf = (bf16*)ws;                            // 16 MiB (reused as hh later)
  bf16* kvbf = (bf16*)(ws + ((size_t)16 << 20));    // 16 MiB
  bf16* WqT = (bf16*)(ws + ((size_t)32 << 20));     // 2 MiB
  bf16* WkvT = (bf16*)(ws + ((size_t)34 << 20));    // 256 KiB
  float2* rtab = (float2*)(ws + ((size_t)34 << 20) + ((size_t)256 << 10));  // 512 KiB
  bf16* WoT = (bf16*)(ws + ((size_t)35 << 20));     // 2 MiB
  bf16* qh = (bf16*)(ws + ((size_t)37 << 20));      // 16 MiB
  bf16* kk = (bf16*)(ws + ((size_t)53 << 20));      // 1 MiB (fragment order)
  bf16* vt = (bf16*)(ws + ((size_t)54 << 20));      // 1 MiB (fragment order)
  bf16* hh = qbf;  // alias: qbf dead after gemm_qkv, hh written by attn

  const int M = Bc * SQc;  // 8192

  rope_tab_build<<<256, 256, 0, stream>>>(rtab);
  cvt_bf16<<<M, 256, 0, stream>>>(q, qbf);
  cvt_bf16<<<M, 256, 0, stream>>>(kv, kvbf);
  transpose_cvt<<<dim3(16, 16), 256, 0, stream>>>(Wq, WqT, 1024, 1024);
  transpose_cvt<<<dim3(2, 16), 256, 0, stream>>>(Wkv, WkvT, 1024, 128);
  transpose_cvt<<<dim3(16, 16), 256, 0, stream>>>(Wo, WoT, 1024, 1024);

  gemm_qkv<<<dim3(64, 9), 256, 0, stream>>>(qbf, WqT, bq, kvbf, WkvT, bkv, rtab,
                                            qh, kk, vt);
  attn_v5<<<Bc * Hc * (SQc / 256), 512, 0, stream>>>(qh, kk, vt, hh);
  gemm_out<<<dim3(64, 8), 256, 0, stream>>>(hh, WoT, bo, (float*)d_out);
}

// Round 10
// 258.026 us; speedup vs baseline: 1.1308x; 1.0132x over previous
//
#include <hip/hip_runtime.h>
#include <math.h>

typedef __bf16 bf16;
typedef __bf16 bf16x4 __attribute__((ext_vector_type(4)));
typedef __bf16 bf16x8 __attribute__((ext_vector_type(8)));
typedef float floatx4 __attribute__((ext_vector_type(4)));

#define MFMA16(a, b, c) __builtin_amdgcn_mfma_f32_16x16x32_bf16(a, b, c, 0, 0, 0)

#if __has_builtin(__builtin_amdgcn_exp2f)
#define EXP2F(x) __builtin_amdgcn_exp2f(x)
#else
#define EXP2F(x) exp2f(x)
#endif

constexpr int Bc = 4, SQc = 2048, SKVc = 2048, Hc = 16, Dc = 64;
// fold 1/sqrt(D) * log2(e) into qh so softmax is exp2 with no extra mul
#define QSCALE 0.18033688011112042f

// Async global->LDS, 16B per lane. LDS dest is wave-uniform base + lane*16;
// global source address is per-lane.
__device__ __forceinline__ void glds16(const bf16* g, bf16* lds_base, int lane) {
#if __has_builtin(__builtin_amdgcn_global_load_lds)
  __builtin_amdgcn_global_load_lds(
      (const __attribute__((address_space(1))) void*)g,
      (__attribute__((address_space(3))) void*)lds_base, 16, 0, 0);
#else
  *(bf16x8*)(lds_base + 8 * lane) = *(const bf16x8*)g;
#endif
}

// ---------------------------------------------------------------------------
// Prepass: fp32 -> bf16 convert (1024 elems per block)
// ---------------------------------------------------------------------------
__global__ void cvt_bf16(const float* __restrict__ in, bf16* __restrict__ out) {
  const size_t i = ((size_t)blockIdx.x * 256 + threadIdx.x) * 4;
  const float4 v = *(const float4*)&in[i];
  bf16x4 o = {(bf16)v.x, (bf16)v.y, (bf16)v.z, (bf16)v.w};
  *(bf16x4*)&out[i] = o;
}

// ---------------------------------------------------------------------------
// Prepass: RoPE cos/sin table. tab[pos*32 + f] = (cos, sin) of
// ang = pos * base^(-2f/64) = pos * 2^(-0.375 f).
// ---------------------------------------------------------------------------
__global__ void rope_tab_build(float2* __restrict__ tab) {
  const int i = blockIdx.x * 256 + threadIdx.x;  // 65536 = 2048 * 32
  const int pos = i >> 5, f = i & 31;
  const float ang = (float)pos * exp2f(-0.375f * (float)f);
  float sn, cs;
  sincosf(ang, &sn, &cs);
  tab[i] = make_float2(cs, sn);
}

// ---------------------------------------------------------------------------
// Prepass: W [K][N] fp32 -> WT [N][K] bf16. grid (N/64, K/64), 256 thr.
// ---------------------------------------------------------------------------
__global__ void transpose_cvt(const float* __restrict__ in, bf16* __restrict__ out,
                              int K, int N) {
  __shared__ bf16 T[64][72];
  const int tid = threadIdx.x;
  const int n0 = blockIdx.x * 64, k0 = blockIdx.y * 64;
  const int tr = tid >> 4, tc4 = (tid & 15) * 4;
#pragma unroll
  for (int i = 0; i < 4; i++) {
    const int k = tr + 16 * i;
    const float4 v = *(const float4*)&in[(size_t)(k0 + k) * N + n0 + tc4];
    T[tc4 + 0][k] = (bf16)v.x;
    T[tc4 + 1][k] = (bf16)v.y;
    T[tc4 + 2][k] = (bf16)v.z;
    T[tc4 + 3][k] = (bf16)v.w;
  }
  __syncthreads();
  const int nr = tid >> 2, kc = (tid & 3) * 8;
#pragma unroll
  for (int hf = 0; hf < 2; hf++)
    *(bf16x8*)&out[(size_t)(n0 + nr) * K + k0 + kc + 32 * hf] =
        *(const bf16x8*)&T[nr][kc + 32 * hf];
}

// ---------------------------------------------------------------------------
// Shared 128x64-tile / BK=64 K-loop (m97-exact inner loop, halved BN).
// Grids were 2.0-2.25 blocks/CU with 128x128 tiles (grid-starved, barrier
// drains exposed); 128x64 doubles block count -> 4+ blocks/CU while keeping
// 16 MFMA per wave per K-step (waves split 2M x 2N, acc[4][2]) and the same
// XOR-swizzled glds16 staging. LDS 24KB. Staging per wave-step: 4 A + 2 B.
// ---------------------------------------------------------------------------
__device__ __forceinline__ void gemm_kloop(const bf16* __restrict__ A,
                                           const bf16* __restrict__ BT, int m0,
                                           int n0, int tid, int wave, int lane,
                                           int m, int g, bf16* As, bf16* Bs,
                                           floatx4 (*acc)[2], int mq, int nq) {
  const int r_ = tid >> 3, p_ = tid & 7;
  const bf16* pA[4];
  const bf16* pB[2];
#pragma unroll
  for (int q = 0; q < 4; q++) {
    const int r = r_ + q * 32;
    const int s = p_ ^ (r & 7);
    pA[q] = &A[(size_t)(m0 + r) * 1024 + 8 * s];
    if (q < 2) pB[q] = &BT[(size_t)(n0 + r) * 1024 + 8 * s];
  }

  for (int k0 = 0; k0 < 1024; k0 += 64) {
    __syncthreads();
#pragma unroll
    for (int q = 0; q < 4; q++)
      glds16(pA[q] + k0, &As[(q * 4 + wave) * 512], lane);
#pragma unroll
    for (int q = 0; q < 2; q++)
      glds16(pB[q] + k0, &Bs[(q * 4 + wave) * 512], lane);
    __syncthreads();  // drains vmcnt -> LDS tiles visible

    bf16x8 bb[2][2];
#pragma unroll
    for (int j = 0; j < 2; j++) {
      const int row = nq + 16 * j + m;
#pragma unroll
      for (int kh = 0; kh < 2; kh++)
        bb[j][kh] = *(const bf16x8*)&Bs[row * 64 + 8 * ((g + 4 * kh) ^ (row & 7))];
    }
#pragma unroll
    for (int i = 0; i < 4; i++) {
      const int row = mq + 16 * i + m;
      const bf16x8 a0 = *(const bf16x8*)&As[row * 64 + 8 * (g ^ (row & 7))];
      const bf16x8 a1 = *(const bf16x8*)&As[row * 64 + 8 * ((g + 4) ^ (row & 7))];
#pragma unroll
      for (int j = 0; j < 2; j++) {
        acc[i][j] = MFMA16(a0, bb[j][0], acc[i][j]);
        acc[i][j] = MFMA16(a1, bb[j][1], acc[i][j]);
      }
    }
  }
}

// ---------------------------------------------------------------------------
// Fused Q-proj + KV-proj. grid (64, 18): y<16 -> Q tiles (RoPE+QSCALE -> qh),
// y==16 -> K tile (RoPE, fragment order), y==17 -> V tile (fragment order).
//   K elem (pos,d) -> chunk=(pos>>4)*2+(d>>5), lane=((d>>3)&3)*16+(pos&15), e=d&7
//   V elem (pos,d) -> chunk=(pos>>6)*8+(d>>4)*2+((pos>>5)&1),
//                     lane=((pos>>3)&3)*16+(d&15), e=pos&7
// ---------------------------------------------------------------------------
__global__ __launch_bounds__(256, 4) void gemm_qkv(
    const bf16* __restrict__ qA, const bf16* __restrict__ qBT,
    const float* __restrict__ qb, const bf16* __restrict__ kvA,
    const bf16* __restrict__ kvBT, const float* __restrict__ kvb,
    const float2* __restrict__ tab, bf16* __restrict__ qh,
    bf16* __restrict__ kko, bf16* __restrict__ vto) {
  __shared__ bf16 As[128 * 64];
  __shared__ bf16 Bs[64 * 64];

  const int tid = threadIdx.x, lane = tid & 63, wave = tid >> 6;
  const int m = lane & 15, g = lane >> 4;
  const int m0 = blockIdx.x * 128;
  const bool isQ = (blockIdx.y < 16);
  const int n0 = isQ ? blockIdx.y * 64 : (blockIdx.y - 16) * 64;
  const bf16* A = isQ ? qA : kvA;
  const bf16* BT = isQ ? qBT : kvBT;
  const float* bias = isQ ? qb : kvb;
  const int mq = (wave >> 1) * 64, nq = (wave & 1) * 32;

  floatx4 z = {0.f, 0.f, 0.f, 0.f};
  floatx4 acc[4][2];
#pragma unroll
  for (int i = 0; i < 4; i++)
#pragma unroll
    for (int j = 0; j < 2; j++) acc[i][j] = z;

  gemm_kloop(A, BT, m0, n0, tid, wave, lane, m, g, As, Bs, acc, mq, nq);

  const int rq = 4 * g;
#pragma unroll
  for (int j = 0; j < 2; j++) {
    const int col = n0 + nq + 16 * j + m;
    const float bv = bias[col];
#pragma unroll
    for (int i = 0; i < 4; i++) {
#pragma unroll
      for (int r = 0; r < 4; r++) {
        const int row = m0 + mq + 16 * i + rq + r;
        float v = acc[i][j][r] + bv;
        const float vp = __shfl_xor(v, 1);
        if (isQ) {
          const int d = col & 63, hh = col >> 6;
          const int pos = row & (SQc - 1), b = row >> 11;
          const float2 cssn = tab[pos * 32 + (d >> 1)];
          const float res = (d & 1) ? (v * cssn.x + vp * cssn.y)
                                    : (v * cssn.x - vp * cssn.y);
          qh[(((size_t)(b * Hc + hh) * SQc) + pos) * Dc + d] = (bf16)(res * QSCALE);
        } else {
          const int pos = row & (SKVc - 1), b = row >> 11;
          const size_t fb = (size_t)b * (SKVc * Dc);
          if (col < 64) {  // block-uniform: y==16 -> K with RoPE
            const int d = col;
            const float2 cssn = tab[pos * 32 + (d >> 1)];
            const float res = (d & 1) ? (v * cssn.x + vp * cssn.y)
                                      : (v * cssn.x - vp * cssn.y);
            const int kc = (pos >> 4) * 2 + (d >> 5);
            const int kl = ((d >> 3) & 3) * 16 + (pos & 15);
            kko[fb + (size_t)kc * 512 + kl * 8 + (d & 7)] = (bf16)res;
          } else {
            const int d = col - 64;
            const int vc = (pos >> 6) * 8 + (d >> 4) * 2 + ((pos >> 5) & 1);
            const int vl = ((pos >> 3) & 3) * 16 + (d & 15);
            vto[fb + (size_t)vc * 512 + vl * 8 + (pos & 7)] = (bf16)v;
          }
        }
      }
    }
  }
}

// ---------------------------------------------------------------------------
// O-projection: fp32 out. grid (64, 16).
// ---------------------------------------------------------------------------
__global__ __launch_bounds__(256, 4) void gemm_out(
    const bf16* __restrict__ A, const bf16* __restrict__ BT,
    const float* __restrict__ bias, float* __restrict__ out) {
  __shared__ bf16 As[128 * 64];
  __shared__ bf16 Bs[64 * 64];

  const int tid = threadIdx.x, lane = tid & 63, wave = tid >> 6;
  const int m = lane & 15, g = lane >> 4;
  const int m0 = blockIdx.x * 128, n0 = blockIdx.y * 64;
  const int mq = (wave >> 1) * 64, nq = (wave & 1) * 32;

  floatx4 z = {0.f, 0.f, 0.f, 0.f};
  floatx4 acc[4][2];
#pragma unroll
  for (int i = 0; i < 4; i++)
#pragma unroll
    for (int j = 0; j < 2; j++) acc[i][j] = z;

  gemm_kloop(A, BT, m0, n0, tid, wave, lane, m, g, As, Bs, acc, mq, nq);

  const int rq = 4 * g;
#pragma unroll
  for (int j = 0; j < 2; j++) {
    const int col = n0 + nq + 16 * j + m;
    const float bv = bias[col];
#pragma unroll
    for (int i = 0; i < 4; i++)
#pragma unroll
      for (int r = 0; r < 4; r++) {
        const int row = m0 + mq + 16 * i + rq + r;
        out[(size_t)row * 1024 + col] = acc[i][j][r] + bv;
      }
  }
}

// ---------------------------------------------------------------------------
// Flash attention v10 + T5 setprio: LDS-shared K/V. 8-wave (512-thr) blocks,
// 32 q-rows per wave, grid 512 -> 16 waves/CU. Fragment-ordered K/V staged
// once per block per iter via global_load_lds; K double-buffered, V single-
// buffered; 2 barriers/iter. setprio(1) wraps the phase-2 MFMA cluster
// (m191: +4-7% on multi-block attn).
// ---------------------------------------------------------------------------
__global__ __launch_bounds__(512, 4) void attn_v5(
    const bf16* __restrict__ qh, const bf16* __restrict__ kk,
    const bf16* __restrict__ vt, bf16* __restrict__ hout) {
  const int bid = blockIdx.x;
  const int qt = bid & 7, h = (bid >> 3) & 15, b = bid >> 7;
  const int tid = threadIdx.x, lane = tid & 63, wave = tid >> 6;  // 8 waves
  const int m = lane & 15, g = lane >> 4;

  __shared__ bf16 Kb[2][4096];       // 16 KiB: K tile double buffer
  __shared__ bf16 Vb[4096];          // 8 KiB: V tile
  __shared__ bf16 Pb[8][2][16][68];  // 34 KiB: per-wave private P relayout

  const int q0 = qt * 256 + wave * 32;
  // Q fragments (B-operand: n=q in lane&15, k=d)
  const bf16* qp = qh + (((size_t)(b * Hc + h) * SQc) + q0 + m) * Dc + 8 * g;
  bf16x8 bq[2][2];
#pragma unroll
  for (int s = 0; s < 2; s++) {
    bq[s][0] = *(const bf16x8*)(qp + (size_t)(16 * s) * Dc);
    bq[s][1] = *(const bf16x8*)(qp + (size_t)(16 * s) * Dc + 32);
  }

  const bf16 one = (bf16)1.0f;
  const bf16x8 ones = {one, one, one, one, one, one, one, one};

  floatx4 z = {0.f, 0.f, 0.f, 0.f};
  floatx4 accO[2][4];
  floatx4 lacc[2] = {z, z};
#pragma unroll
  for (int s = 0; s < 2; s++)
#pragma unroll
    for (int t = 0; t < 4; t++) accO[s][t] = z;

  // fragment-ordered global bases (per-lane: +16B*lane)
  const size_t fb = (size_t)b * (SKVc * Dc);
  const bf16* kg = kk + fb + 8 * lane;
  const bf16* vg = vt + fb + 8 * lane;

  // prologue: stage K(0); wave w stages chunk w (1 KiB each)
  glds16(kg + (size_t)wave * 512, &Kb[0][wave * 512], lane);
  __syncthreads();

  for (int it = 0; it < 32; ++it) {
    const int cur = it & 1;
    // top barrier: previous iter's Vb reads complete before restaging
    if (it) __syncthreads();
    // stage V(it) and K(it+1): wave w handles chunk w of each
    glds16(vg + (size_t)(it * 8 + wave) * 512, &Vb[wave * 512], lane);
    if (it + 1 < 32)
      glds16(kg + (size_t)((it + 1) * 8 + wave) * 512, &Kb[cur ^ 1][wave * 512],
             lane);

    // ---- phase 1: QK + exp2 + Pb write (K tile shared from LDS) ----
    bf16x8 kfr[4][2];
#pragma unroll
    for (int c = 0; c < 4; c++) {
      kfr[c][0] = *(const bf16x8*)&Kb[cur][(2 * c + 0) * 512 + 8 * lane];
      kfr[c][1] = *(const bf16x8*)&Kb[cur][(2 * c + 1) * 512 + 8 * lane];
    }
#pragma unroll
    for (int s = 0; s < 2; s++) {
#pragma unroll
      for (int c = 0; c < 4; c++) {
        floatx4 sv = MFMA16(kfr[c][0], bq[s][0], z);
        sv = MFMA16(kfr[c][1], bq[s][1], sv);
        bf16x4 pk = {(bf16)EXP2F(sv[0]), (bf16)EXP2F(sv[1]), (bf16)EXP2F(sv[2]),
                     (bf16)EXP2F(sv[3])};
        *(bf16x4*)&Pb[wave][s][m][16 * c + 4 * g] = pk;
      }
    }
    __syncthreads();  // drains vmcnt: V(it)/K(it+1) landed; Kb[cur] reads done

    // ---- phase 2: read V fragments from LDS, P from Pb, accumulate ----
    bf16x8 vf[4][2];
#pragma unroll
    for (int t = 0; t < 4; t++) {
      vf[t][0] = *(const bf16x8*)&Vb[(2 * t + 0) * 512 + 8 * lane];
      vf[t][1] = *(const bf16x8*)&Vb[(2 * t + 1) * 512 + 8 * lane];
    }
    __builtin_amdgcn_s_setprio(1);
#pragma unroll
    for (int s = 0; s < 2; s++) {
      const bf16x8 pa0 = *(const bf16x8*)&Pb[wave][s][m][8 * g];
      const bf16x8 pa1 = *(const bf16x8*)&Pb[wave][s][m][32 + 8 * g];
      lacc[s] = MFMA16(pa0, ones, lacc[s]);
      lacc[s] = MFMA16(pa1, ones, lacc[s]);
#pragma unroll
      for (int t = 0; t < 4; t++) {
        accO[s][t] = MFMA16(pa0, vf[t][0], accO[s][t]);
        accO[s][t] = MFMA16(pa1, vf[t][1], accO[s][t]);
      }
    }
    __builtin_amdgcn_s_setprio(0);
  }

  // ---- normalize and store h[b][s][h*64+d] ----
#pragma unroll
  for (int s = 0; s < 2; s++) {
    floatx4 inv;
#pragma unroll
    for (int r = 0; r < 4; r++) inv[r] = 1.0f / lacc[s][r];
#pragma unroll
    for (int t = 0; t < 4; t++)
#pragma unroll
      for (int r = 0; r < 4; r++) {
        const int qrow = q0 + 16 * s + 4 * g + r;
        hout[((size_t)(b * SQc + qrow)) * (Hc * Dc) + h * Dc + 16 * t + m] =
            (bf16)(accO[s][t][r] * inv[r]);
      }
  }
}

// ---------------------------------------------------------------------------
extern "C" void kernel_launch(void* const* d_in, const int* in_sizes, int n_in,
                              void* d_out, int out_size, void* d_ws, size_t ws_size,
                              hipStream_t stream) {
  const float* q = (const float*)d_in[0];
  const float* kv = (const float*)d_in[1];
  const float* Wq = (const float*)d_in[2];
  const float* bq = (const float*)d_in[3];
  const float* Wkv = (const float*)d_in[4];
  const float* bkv = (const float*)d_in[5];
  const float* Wo = (const float*)d_in[6];
  const float* bo = (const float*)d_in[7];

  char* ws = (char*)d_ws;
  bf16* qbf = (bf16*)ws;                            // 16 MiB (reused as hh later)
  bf16* kvbf = (bf16*)(ws + ((size_t)16 << 20));    // 16 MiB
  bf16* WqT = (bf16*)(ws + ((size_t)32 << 20));     // 2 MiB
  bf16* WkvT = (bf16*)(ws + ((size_t)34 << 20));    // 256 KiB
  float2* rtab = (float2*)(ws + ((size_t)34 << 20) + ((size_t)256 << 10));  // 512 KiB
  bf16* WoT = (bf16*)(ws + ((size_t)35 << 20));     // 2 MiB
  bf16* qh = (bf16*)(ws + ((size_t)37 << 20));      // 16 MiB
  bf16* kk = (bf16*)(ws + ((size_t)53 << 20));      // 1 MiB (fragment order)
  bf16* vt = (bf16*)(ws + ((size_t)54 << 20));      // 1 MiB (fragment order)
  bf16* hh = qbf;  // alias: qbf dead after gemm_qkv, hh written by attn

  const int M = Bc * SQc;  // 8192

  rope_tab_build<<<256, 256, 0, stream>>>(rtab);
  cvt_bf16<<<M, 256, 0, stream>>>(q, qbf);
  cvt_bf16<<<M, 256, 0, stream>>>(kv, kvbf);
  transpose_cvt<<<dim3(16, 16), 256, 0, stream>>>(Wq, WqT, 1024, 1024);
  transpose_cvt<<<dim3(2, 16), 256, 0, stream>>>(Wkv, WkvT, 1024, 128);
  transpose_cvt<<<dim3(16, 16), 256, 0, stream>>>(Wo, WoT, 1024, 1024);

  gemm_qkv<<<dim3(64, 18), 256, 0, stream>>>(qbf, WqT, bq, kvbf, WkvT, bkv, rtab,
                                             qh, kk, vt);
  attn_v5<<<Bc * Hc * (SQc / 256), 512, 0, stream>>>(qh, kk, vt, hh);
  gemm_out<<<dim3(64, 16), 256, 0, stream>>>(hh, WoT, bo, (float*)d_out);
}